// Round 9
// baseline (216.805 us; speedup 1.0000x reference)
//
#include <hip/hip_runtime.h>
#include <hip/hip_bf16.h>

// Problem constants
#define NT 8192            // tokens
#define NQB 6              // qubits
// Attention kernel tiling (r4 verified config)
#define JSPLIT 16
#define JSLICE (NT / JSPLIT)     // 512 keys per block
#define CHUNK 64                 // keys staged per LDS chunk
#define NCHUNK (JSLICE / CHUNK)  // 8
#define IPW 32                   // query rows per wave (2 rowtiles of 16)
#define WPB 4                    // waves per block
#define IPB (IPW * WPB)          // 128 rows per block
#define NBI (NT / IPB)           // 64 i-blocks

typedef __bf16 bf16x8 __attribute__((ext_vector_type(8)));
typedef float f32x4 __attribute__((ext_vector_type(4)));

static __device__ __forceinline__ unsigned int pack_bf2(float a, float b) {
  unsigned short lo = __builtin_bit_cast(unsigned short, __float2bfloat16(a));
  unsigned short hi = __builtin_bit_cast(unsigned short, __float2bfloat16(b));
  return (unsigned int)lo | ((unsigned int)hi << 16);
}

// one CNOT's index map: src(p) = p ^ (bit_c(p) ? mask_t : 0)  (an involution)
static __device__ __forceinline__ int cnot_src(int p, int q) {
  const int mc = 1 << (5 - q);
  const int mt = 1 << (5 - ((q + 1) % NQB));
  return (p & mc) ? (p ^ mt) : p;
}

// ---------------------------------------------------------------------------
// Kernel 1: statevector prep (verified r3-r6 body) + zero-init of the
// attn accumulator/counters (workspace is re-poisoned 0xAA before every
// launch, so the zeroing must happen on-stream every call; folding it here
// avoids a third dispatch).
// ---------------------------------------------------------------------------
__global__ __launch_bounds__(256) void prep_kernel(
    const float* __restrict__ x, const float* __restrict__ pq,
    const float* __restrict__ pk, const float* __restrict__ pv,
    unsigned int* __restrict__ Are, unsigned int* __restrict__ Bk,
    float4* __restrict__ V4, float* __restrict__ acc, int* __restrict__ cnt)
{
  // zero acc (8192*8 floats = 256 KiB) and cnt (64 ints) using the first blocks
  if (blockIdx.x < 256) {
    acc[blockIdx.x * 256 + threadIdx.x] = 0.f;
  } else if (blockIdx.x == 256 && threadIdx.x < NBI) {
    cnt[threadIdx.x] = 0;
  }

  const int wid  = blockIdx.x * 4 + (threadIdx.x >> 6);
  const int lane = threadIdx.x & 63;
  const int set  = wid >> 13;          // / 8192
  const int tok  = wid & (NT - 1);
  const float* pp = (set == 0) ? pq : ((set == 1) ? pk : pv);

  // sigma(l) = src_0(src_1(...src_5(l)))   [final[l] = old[sigma(l)]]
  int m = lane;
#pragma unroll
  for (int q = 5; q >= 0; --q) m = cnot_src(m, q);
  // sigma^{-1}(l) = src_5(src_4(...src_0(l)))
  int inv = lane;
#pragma unroll
  for (int q = 0; q < 6; ++q) inv = cnot_src(inv, q);

  // product state (through layer-0) evaluated at index m
  float R = 1.f, phi = 0.f;
#pragma unroll
  for (int q = 0; q < 6; ++q) {
    const float t = 0.5f * (x[tok * NQB + q] + pp[q * 2 + 0]);
    const float s = __sinf(t), c = __cosf(t);
    const float bh = 0.5f * pp[q * 2 + 1];
    if ((m >> (5 - q)) & 1) { R *= s; phi += bh; }
    else                    { R *= c; phi -= bh; }
  }
  float re = R * __cosf(phi), im = R * __sinf(phi);

  // layer-1 RYs (entangled now -> shuffles)
#pragma unroll
  for (int q = 0; q < 6; ++q) {
    const int mask = 1 << (5 - q);
    const float t = 0.5f * pp[2 * NQB + q * 2 + 0];
    const float s = __sinf(t), c = __cosf(t);
    const float pre = __shfl_xor(re, mask, 64);
    const float pim = __shfl_xor(im, mask, 64);
    const float se = (lane & mask) ? s : -s;
    re = fmaf(se, pre, c * re);
    im = fmaf(se, pim, c * im);
  }
  // layer-1 RZs combined into one phase per lane
  float phi2 = 0.f;
#pragma unroll
  for (int q = 0; q < 6; ++q) {
    const float bh = 0.5f * pp[2 * NQB + q * 2 + 1];
    phi2 += (lane & (1 << (5 - q))) ? bh : -bh;
  }
  const float s2 = __sinf(phi2), c2 = __cosf(phi2);
  const float fre = re * c2 - im * s2;
  const float fim = re * s2 + im * c2;

  if (set == 0) {
    Are[tok * 64 + inv] = pack_bf2(fre, fim);     // [qr, qi]
  } else if (set == 1) {
    Bk[tok * 64 + inv] = pack_bf2(fre, fim);      // [kr, ki]
  } else {
    const float prob = fre * fre + fim * fim;     // prob of final basis index 'inv'
    float vq[NQB];
#pragma unroll
    for (int q = 0; q < NQB; ++q) {
      float v = (inv & (1 << (5 - q))) ? -prob : prob;  // sign = 1-2*bit
#pragma unroll
      for (int off = 1; off < 64; off <<= 1) v += __shfl_xor(v, off, 64);
      vq[q] = v;
    }
    if (lane == 0) {
      V4[tok * 2 + 0] = make_float4(vq[0], vq[1], vq[2], vq[3]);
      V4[tok * 2 + 1] = make_float4(vq[4], vq[5], 0.f, 0.f);
    }
  }
}

// ---------------------------------------------------------------------------
// Kernel 2: fused swap-test attention + combine (last-block-done).
//  Main loop = VERIFIED r4 body (interleaved MFMA, JSPLIT=16).
//  Epilogue: device-scope fp32 atomicAdd of (6 num + den) per row into acc
//  (atomics are cross-XCD coherent at the L3 coherence point — plain stores
//  are NOT, per G16), then a per-i-block counter; the 16th j-block for an
//  i-block normalizes and writes the 128 output rows. No grid sync, no
//  co-residency assumption, no extra launch.
// MFMA 16x16x32 bf16 layouts:
//   A: row = lane&15, k = (lane>>4)*8 + j
//   B: col = lane&15, k = (lane>>4)*8 + j
//   D: col = lane&15, row = (lane>>4)*4 + reg
// ---------------------------------------------------------------------------
__global__ __launch_bounds__(256, 2) void attn_kernel(
    const uint4* __restrict__ Are, const uint4* __restrict__ Bk,
    const float4* __restrict__ V4, float* __restrict__ acc,
    int* __restrict__ cnt, float* __restrict__ out)
{
  __shared__ uint4 kbuf[CHUNK * 17];   // row stride 17 uint4 = 272B
  __shared__ float4 vbuf[CHUNK * 2];   // 8 floats per key (6 used)
  __shared__ int lastFlag;

  const int tid  = threadIdx.x;
  const int lane = tid & 63;
  const int wave = tid >> 6;
  const int col  = lane & 15;
  const int quad = lane >> 4;

  const int ib = blockIdx.x & (NBI - 1);
  const int js = blockIdx.x / NBI;
  const int ibase = ib * IPB + wave * IPW;
  const int jbase0 = js * JSLICE;

  // A fragments; aIm derived in-register: (qr,qi) -> (qi,-qr) per packed u32
  bf16x8 aRe[2][4], aIm[2][4];
#pragma unroll
  for (int rt = 0; rt < 2; ++rt) {
    const int row = ibase + rt * 16 + col;
    const uint4* pr = Are + row * 16 + quad;   // row = 16 uint4 (256B)
#pragma unroll
    for (int s = 0; s < 4; ++s) {
      const uint4 u = pr[s * 4];
      uint4 w;
      w.x = ((u.x << 16) | (u.x >> 16)) ^ 0x80000000u;
      w.y = ((u.y << 16) | (u.y >> 16)) ^ 0x80000000u;
      w.z = ((u.z << 16) | (u.z >> 16)) ^ 0x80000000u;
      w.w = ((u.w << 16) | (u.w >> 16)) ^ 0x80000000u;
      aRe[rt][s] = __builtin_bit_cast(bf16x8, u);
      aIm[rt][s] = __builtin_bit_cast(bf16x8, w);
    }
  }

  float den[8];
  float num[8][6];
#pragma unroll
  for (int r = 0; r < 8; ++r) {
    den[r] = 0.f;
#pragma unroll
    for (int q = 0; q < 6; ++q) num[r][q] = 0.f;
  }

#pragma unroll 1
  for (int c = 0; c < NCHUNK; ++c) {
    const int jb = jbase0 + c * CHUNK;
    __syncthreads();
    // stage 64 keys (16KB) cooperatively, coalesced 16B per thread
#pragma unroll
    for (int r = 0; r < 4; ++r) {
      const int idx = r * 256 + tid;
      kbuf[(idx >> 4) * 17 + (idx & 15)] = Bk[(jb + (idx >> 4)) * 16 + (idx & 15)];
    }
    if (tid < 2 * CHUNK) vbuf[tid] = V4[jb * 2 + tid];
    __syncthreads();

#pragma unroll
    for (int ct = 0; ct < 4; ++ct) {
      const int keyl = ct * 16 + col;
      bf16x8 bfr[4];
#pragma unroll
      for (int s = 0; s < 4; ++s)
        bfr[s] = __builtin_bit_cast(bf16x8, kbuf[keyl * 17 + s * 4 + quad]);
      const float4 v01 = vbuf[keyl * 2 + 0];
      const float4 v23 = vbuf[keyl * 2 + 1];
      const float vv[6] = {v01.x, v01.y, v01.z, v01.w, v23.x, v23.y};
#pragma unroll
      for (int rt = 0; rt < 2; ++rt) {
        f32x4 aR = {0.f, 0.f, 0.f, 0.f};
        f32x4 aI = {0.f, 0.f, 0.f, 0.f};
#pragma unroll
        for (int s = 0; s < 4; ++s) {
          aR = __builtin_amdgcn_mfma_f32_16x16x32_bf16(aRe[rt][s], bfr[s], aR, 0, 0, 0);
          aI = __builtin_amdgcn_mfma_f32_16x16x32_bf16(aIm[rt][s], bfr[s], aI, 0, 0, 0);
        }
#pragma unroll
        for (int r = 0; r < 4; ++r) {
          const float f = aR[r] * aR[r] + aI[r] * aI[r];
          const float w = __expf(f);               // f in [0,1]: no max-shift
          const int rr = rt * 4 + r;
          den[rr] += w;
#pragma unroll
          for (int q = 0; q < 6; ++q) num[rr][q] = fmaf(w, vv[q], num[rr][q]);
        }
      }
    }
  }

  // reduce across the 16 lanes of each quad-group
#pragma unroll
  for (int rr = 0; rr < 8; ++rr) {
#pragma unroll
    for (int off = 1; off < 16; off <<= 1) {
      den[rr] += __shfl_xor(den[rr], off, 64);
#pragma unroll
      for (int q = 0; q < 6; ++q) num[rr][q] += __shfl_xor(num[rr][q], off, 64);
    }
  }

  // accumulate this j-slice's contribution (device-scope atomics)
  if (col == 0) {
#pragma unroll
    for (int rt = 0; rt < 2; ++rt) {
#pragma unroll
      for (int r = 0; r < 4; ++r) {
        const int row = ibase + rt * 16 + quad * 4 + r;
        float* a = acc + (size_t)row * 8;
        const int rr = rt * 4 + r;
#pragma unroll
        for (int q = 0; q < 6; ++q) atomicAdd(a + q, num[rr][q]);
        atomicAdd(a + 6, den[rr]);
      }
    }
  }

  // last j-block for this i-block normalizes and writes the output rows
  __threadfence();                       // release our adds
  __syncthreads();                       // all waves' atomics issued+fenced
  if (tid == 0) lastFlag = (atomicAdd(&cnt[ib], 1) == JSPLIT - 1);
  __syncthreads();
  if (lastFlag) {
    __threadfence();                     // acquire: see all 16 slices' adds
    const int ib0 = ib * IPB;
    for (int r = tid; r < IPB; r += 256) {
      const int row = ib0 + r;
      float v[7];
#pragma unroll
      for (int q = 0; q < 7; ++q)
        v[q] = __hip_atomic_load(acc + (size_t)row * 8 + q,
                                 __ATOMIC_RELAXED, __HIP_MEMORY_SCOPE_AGENT);
      const float inv = 1.0f / v[6];
#pragma unroll
      for (int q = 0; q < 6; ++q) out[row * 6 + q] = v[q] * inv;
    }
  }
}

// ---------------------------------------------------------------------------
// Workspace layout (bytes):
//   Are @ 0          : 8192*64*4 = 2 MiB   (bf16 pairs packed in u32)
//   Bk  @ 2 MiB      : 2 MiB
//   V   @ 4 MiB      : 8192*8*4 = 256 KiB  (fp32, padded to 8)
//   acc @ 4.25 MiB   : 8192*8*4 = 256 KiB  (fp32 atomic accumulator)
//   cnt @ 4.5 MiB    : 64*4 B              (per-i-block arrival counter)
//   total ~4.5 MiB
// ---------------------------------------------------------------------------
extern "C" void kernel_launch(void* const* d_in, const int* in_sizes, int n_in,
                              void* d_out, int out_size, void* d_ws, size_t ws_size,
                              hipStream_t stream) {
  const float* x  = (const float*)d_in[0];
  const float* pq = (const float*)d_in[1];
  const float* pk = (const float*)d_in[2];
  const float* pv = (const float*)d_in[3];
  char* ws = (char*)d_ws;
  unsigned int* Are = (unsigned int*)(ws);
  unsigned int* Bk  = (unsigned int*)(ws + (size_t)(2u << 20));
  float4*       V4  = (float4*)(ws + (size_t)(4u << 20));
  float*        acc = (float*)(ws + (size_t)(4u << 20) + (size_t)(256u << 10));
  int*          cnt = (int*)(ws + (size_t)(4u << 20) + (size_t)(512u << 10));

  prep_kernel<<<(NT * 3) / 4, 256, 0, stream>>>(x, pq, pk, pv, Are, Bk, V4, acc, cnt);
  attn_kernel<<<NBI * JSPLIT, 256, 0, stream>>>((const uint4*)Are, (const uint4*)Bk,
                                                (const float4*)V4, acc, cnt,
                                                (float*)d_out);
}